// Round 1
// baseline (704.619 us; speedup 1.0000x reference)
//
#include <hip/hip_runtime.h>

// Problem constants (from reference)
#define I_CNT 100000
#define U_CNT 131072
#define E_DIM 64
#define IE (I_CNT * E_DIM)          // 6,400,000 floats
#define UE ((size_t)U_CNT * E_DIM)  // 8,388,608 floats

#define DEPTH 8   // outstanding x-gathers per wave (software pipeline ring)

// ---------------- threefry2x32 (verified vs Random123 test vector) ----------------
__device__ __forceinline__ unsigned rotl32(unsigned v, int n) {
    return (v << n) | (v >> (32 - n));
}
__device__ __forceinline__ void threefry2x32(unsigned k0, unsigned k1,
                                             unsigned x0, unsigned x1,
                                             unsigned& o0, unsigned& o1) {
    unsigned k2 = k0 ^ k1 ^ 0x1BD11BDAu;
    x0 += k0; x1 += k1;
#define RND(r) { x0 += x1; x1 = rotl32(x1, r); x1 ^= x0; }
    RND(13) RND(15) RND(26) RND(6)   x0 += k1; x1 += k2 + 1u;
    RND(17) RND(29) RND(16) RND(24)  x0 += k2; x1 += k0 + 2u;
    RND(13) RND(15) RND(26) RND(6)   x0 += k0; x1 += k1 + 3u;
    RND(17) RND(29) RND(16) RND(24)  x0 += k1; x1 += k2 + 4u;
    RND(13) RND(15) RND(26) RND(6)   x0 += k2; x1 += k0 + 5u;
#undef RND
    o0 = x0; o1 = x1;
}

// Dropout mask, MEASURED (R8 discriminator probe, exact hit at 212.5):
// partitionable threefry, ctr=(0,e), bits = out0 ^ out1 (XOR fold),
// u = bitcast((bits>>9)|0x3f800000)-1; keep iff u < 0.8; rescale 1/0.8.
__device__ __forceinline__ float dropout_mul(unsigned e) {
    unsigned o0, o1;
    threefry2x32(0u, 42u, 0u, e, o0, o1);
    const unsigned bits = o0 ^ o1;
    const float u = __uint_as_float((bits >> 9) | 0x3f800000u) - 1.0f;
    return (u < 0.8f) ? 1.25f : 0.0f;
}

// Uniform broadcasts with runtime (wave-uniform) lane index -> v_readlane SGPR form.
__device__ __forceinline__ int rl_i(int v, int l) {
    return __builtin_amdgcn_readlane(v, l);
}
__device__ __forceinline__ float rl_f(float v, int l) {
    return __int_as_float(__builtin_amdgcn_readlane(__float_as_int(v), l));
}

// ---------------- row_ptr builder (rows are sorted) ----------------
// row_ptr[r] = first edge index of row r; row_ptr[n_rows] = nnz.
// Thread e fills the (rows[e-1], rows[e]] range; thread 0 fills [0, rows[0]];
// the last thread fills the tail. Gaps are tiny for this data (dense random rows).
__global__ void build_row_ptr(const int* __restrict__ rows,
                              int* __restrict__ row_ptr,
                              int nnz, int n_rows) {
    const int e = blockIdx.x * blockDim.x + threadIdx.x;
    if (e >= nnz) return;
    const int r  = rows[e];
    const int rp = (e == 0) ? -1 : rows[e - 1];
    for (int q = rp + 1; q <= r; ++q) row_ptr[q] = e;
    if (e == nnz - 1) {
        for (int q = r + 1; q <= n_rows; ++q) row_ptr[q] = nnz;
    }
}

// ---------------- CSR SpMM: one wave per output row ----------------
// lane = embedding dim (E=64 = wave width). Indices/vals for up to 64 edges
// preloaded coalesced by the wave's lanes, broadcast via v_readlane (SGPR
// index, wave-uniform). x-gathers software-pipelined DEPTH deep with STATIC
// ring-slot indices (no runtime-indexed register arrays -> no scratch).
// Register accumulation across the whole row; single coalesced 256B plain
// store per row (covers empty rows with 0) -> no memset, no atomics.
template <bool DROPOUT>
__global__ __launch_bounds__(256) void spmm_csr(const float* __restrict__ vals,
                                                const int* __restrict__ row_ptr,
                                                const int* __restrict__ cols,
                                                const float* __restrict__ x,
                                                float* __restrict__ y,
                                                int n_rows) {
    const int lane = threadIdx.x & 63;
    const int row  = blockIdx.x * (blockDim.x >> 6) + (threadIdx.x >> 6);
    if (row >= n_rows) return;

    const int start = row_ptr[row];
    const int end   = row_ptr[row + 1];

    float acc = 0.0f;
    for (int b = start; b < end; b += 64) {
        const int n = min(64, end - b);  // edges in this block (wave-uniform)

        // Coalesced preload: lane j holds col/val of edge b+j (j < n).
        const int idx = cols[b + ((lane < n) ? lane : 0)];
        float v = 0.0f;
        if (lane < n) {
            v = vals[b + lane];
            if (DROPOUT) v *= dropout_mul((unsigned)(b + lane));
        }

        // Prologue: fill the gather ring (slot u <- edge u).
        float xv[DEPTH];
#pragma unroll
        for (int u = 0; u < DEPTH; ++u) {
            if (u < n) {  // uniform branch
                const int c = rl_i(idx, u);
                xv[u] = x[((size_t)(unsigned)c << 6) + lane];
            }
        }

        // Main loop: DEPTH edges per iteration, static slot indices,
        // guarded refill DEPTH ahead (uniform scalar branch).
        int e = 0;
        for (; e + DEPTH <= n; e += DEPTH) {
#pragma unroll
            for (int u = 0; u < DEPTH; ++u) {
                const float xc  = xv[u];
                const int   nxt = e + u + DEPTH;
                if (nxt < n) {
                    const int c = rl_i(idx, nxt);
                    xv[u] = x[((size_t)(unsigned)c << 6) + lane];
                }
                acc = fmaf(rl_f(v, e + u), xc, acc);
            }
        }

        // Tail: slot u holds edge e+u (from last refill or prologue).
#pragma unroll
        for (int u = 0; u < DEPTH; ++u) {
            if (e + u < n) acc = fmaf(rl_f(v, e + u), xv[u], acc);
        }
    }

    // Single coalesced 256B store; zero for empty rows (replaces memset).
    y[((size_t)row << 6) + lane] = acc;
}

static inline int spmm_blocks(int n_rows) {
    return (n_rows + 3) / 4;  // 4 waves (256 threads) per block, 1 row/wave
}

extern "C" void kernel_launch(void* const* d_in, const int* in_sizes, int n_in,
                              void* d_out, int out_size, void* d_ws, size_t ws_size,
                              hipStream_t stream) {
    const float* item_emb = (const float*)d_in[0];
    const float* S_vals   = (const float*)d_in[1];
    const int*   S_rows   = (const int*)  d_in[2];
    const int*   S_cols   = (const int*)  d_in[3];
    const float* urm_vals = (const float*)d_in[4];
    const int*   urm_rows = (const int*)  d_in[5];
    const int*   urm_cols = (const int*)  d_in[6];

    const int nnzS = in_sizes[1];
    const int nnzU = in_sizes[4];

    float* user_out = (float*)d_out;          // U*E floats (output 0)
    float* x_out    = (float*)d_out + UE;     // I*E floats (output 1)

    // Workspace: row_ptr for S (I+1 ints) and URM (U+1 ints), 256B-aligned.
    int* rpS = (int*)d_ws;
    size_t rpS_bytes = ((size_t)(I_CNT + 1) * sizeof(int) + 255) & ~(size_t)255;
    int* rpU = (int*)((char*)d_ws + rpS_bytes);

    const dim3 blk(256);

    // Build CSR row pointers (rows arrays are sorted).
    build_row_ptr<<<(nnzS + 255) / 256, blk, 0, stream>>>(S_rows, rpS, nnzS, I_CNT);
    build_row_ptr<<<(nnzU + 255) / 256, blk, 0, stream>>>(urm_rows, rpU, nnzU, U_CNT);

    // hop 1: item_emb -> x_out (x1)
    spmm_csr<false><<<spmm_blocks(I_CNT), blk, 0, stream>>>(
        S_vals, rpS, S_cols, item_emb, x_out, I_CNT);

    // hop 2: x_out -> user region used as temp (x2; IE < UE, fits)
    spmm_csr<false><<<spmm_blocks(I_CNT), blk, 0, stream>>>(
        S_vals, rpS, S_cols, x_out, user_out, I_CNT);

    // hop 3: temp (x2) -> x_out (x3 = final x output)
    spmm_csr<false><<<spmm_blocks(I_CNT), blk, 0, stream>>>(
        S_vals, rpS, S_cols, user_out, x_out, I_CNT);

    // user embeddings: URM_dropout @ x3 -> user_out (every row stored)
    spmm_csr<true><<<spmm_blocks(U_CNT), blk, 0, stream>>>(
        urm_vals, rpU, urm_cols, x_out, user_out, U_CNT);
}

// Round 2
// 411.600 us; speedup vs baseline: 1.7119x; 1.7119x over previous
//
#include <hip/hip_runtime.h>

// Problem constants (from reference)
#define I_CNT 100000
#define U_CNT 131072
#define E_DIM 64
#define UE ((size_t)U_CNT * E_DIM)  // 8,388,608 floats

#define DEPTH 16  // outstanding x-row gathers per wave (register ring)

// ---------------- threefry2x32 (verified vs Random123 test vector) ----------------
__device__ __forceinline__ unsigned rotl32(unsigned v, int n) {
    return (v << n) | (v >> (32 - n));
}
__device__ __forceinline__ void threefry2x32(unsigned k0, unsigned k1,
                                             unsigned x0, unsigned x1,
                                             unsigned& o0, unsigned& o1) {
    unsigned k2 = k0 ^ k1 ^ 0x1BD11BDAu;
    x0 += k0; x1 += k1;
#define RND(r) { x0 += x1; x1 = rotl32(x1, r); x1 ^= x0; }
    RND(13) RND(15) RND(26) RND(6)   x0 += k1; x1 += k2 + 1u;
    RND(17) RND(29) RND(16) RND(24)  x0 += k2; x1 += k0 + 2u;
    RND(13) RND(15) RND(26) RND(6)   x0 += k0; x1 += k1 + 3u;
    RND(17) RND(29) RND(16) RND(24)  x0 += k1; x1 += k2 + 4u;
    RND(13) RND(15) RND(26) RND(6)   x0 += k2; x1 += k0 + 5u;
#undef RND
    o0 = x0; o1 = x1;
}

// Dropout mask, MEASURED (R8 discriminator probe, exact hit at 212.5):
// partitionable threefry, ctr=(0,e), bits = out0 ^ out1 (XOR fold),
// u = bitcast((bits>>9)|0x3f800000)-1; keep iff u < 0.8; rescale 1/0.8.
__device__ __forceinline__ float dropout_mul(unsigned e) {
    unsigned o0, o1;
    threefry2x32(0u, 42u, 0u, e, o0, o1);
    const unsigned bits = o0 ^ o1;
    const float u = __uint_as_float((bits >> 9) | 0x3f800000u) - 1.0f;
    return (u < 0.8f) ? 1.25f : 0.0f;
}

// Compile-time-index lane broadcasts -> v_readlane with immediate.
__device__ __forceinline__ int rl_i(int v, int l) {
    return __builtin_amdgcn_readlane(v, l);
}
__device__ __forceinline__ float rl_f(float v, int l) {
    return __int_as_float(__builtin_amdgcn_readlane(__float_as_int(v), l));
}

// ---------------- row_ptr builder (rows are sorted) ----------------
__global__ void build_row_ptr(const int* __restrict__ rows,
                              int* __restrict__ row_ptr,
                              int nnz, int n_rows) {
    const int e = blockIdx.x * blockDim.x + threadIdx.x;
    if (e >= nnz) return;
    const int r  = rows[e];
    const int rp = (e == 0) ? -1 : rows[e - 1];
    for (int q = rp + 1; q <= r; ++q) row_ptr[q] = e;
    if (e == nnz - 1) {
        for (int q = r + 1; q <= n_rows; ++q) row_ptr[q] = nnz;
    }
}

// ---------------- slotted CSR SpMM: straight-line 64-edge pipeline ----------------
// Wave owns RPW = 2^LOG_RPW consecutive rows, each padded to SLOTS = 64/RPW
// edge slots. lane = embedding dim (E=64 = wave width). Padded slots carry
// v=0 and a col clamped to the row's last real edge (gather re-reads a hot
// line -> L1 hit, no extra L2 traffic). Rare overflow (len > SLOTS) is
// accumulated in a COLD uniform block BEFORE the pipeline, so the 64-slot
// main loop is pure straight-line: compile-time readlane, DEPTH-16 gather
// ring with static slots, unconditional stores at compile-time flush points.
// => precise vmcnt scheduling, full memory-level parallelism, no atomics,
// no memsets (every row stored, zeros included).
// REQUIRES: n_rows % RPW == 0 (holds: 100000 % 2 == 0, 131072 % 1 == 0).
template <bool DROPOUT, int LOG_RPW>
__global__ __launch_bounds__(256) void spmm_slots(const float* __restrict__ vals,
                                                  const int* __restrict__ row_ptr,
                                                  const int* __restrict__ cols,
                                                  const float* __restrict__ x,
                                                  float* __restrict__ y,
                                                  int n_rows, int nnz) {
    constexpr int RPW   = 1 << LOG_RPW;   // rows per wave
    constexpr int SLOTS = 64 >> LOG_RPW;  // edge slots per row

    const int lane = threadIdx.x & 63;
    const int wave = blockIdx.x * (blockDim.x >> 6) + (threadIdx.x >> 6);
    const int r0   = wave << LOG_RPW;
    if (r0 >= n_rows) return;

    // Lane -> (row-of-group q, slot-within-row j); overall slot index == lane.
    const int q  = lane >> (6 - LOG_RPW);
    const int j  = lane & (SLOTS - 1);
    const int rq = r0 + q;

    const int s   = row_ptr[rq];       // per-lane (uniform within each group)
    const int e   = row_ptr[rq + 1];
    const int len = e - s;

    // Preload this slot's col (clamped) and value (0 for padded slots).
    int ce = s + min(j, max(len - 1, 0));
    ce = min(ce, nnz - 1);
    const int idx = cols[ce];
    float v;
    {
        const int ve = min(s + j, nnz - 1);
        float vv = vals[ve];
        if (DROPOUT) vv *= dropout_mul((unsigned)ve);
        v = (j < len) ? vv : 0.0f;
    }

    // COLD path: rows longer than SLOTS (P ~ 1e-5). Uniform branch placed
    // before the pipeline so the hot loop stays branch-free.
    float ovf[RPW];
#pragma unroll
    for (int qq = 0; qq < RPW; ++qq) ovf[qq] = 0.0f;
    if (__any(len > SLOTS)) {
#pragma unroll
        for (int qq = 0; qq < RPW; ++qq) {
            const int rs = rl_i(s, qq * SLOTS);
            const int re = rl_i(e, qq * SLOTS);
            for (int t = rs + SLOTS; t < re; ++t) {
                const int c = cols[t];
                float vv = vals[t];
                if (DROPOUT) vv *= dropout_mul((unsigned)t);
                ovf[qq] = fmaf(vv, x[((size_t)(unsigned)c << 6) + lane], ovf[qq]);
            }
        }
    }

    // HOT path: straight-line 64-slot pipeline.
    float xv[DEPTH];
#pragma unroll
    for (int u = 0; u < DEPTH; ++u) {  // prologue: fill the ring
        const int c = rl_i(idx, u);
        xv[u] = x[((size_t)(unsigned)c << 6) + lane];
    }

    float acc = 0.0f;
#pragma unroll
    for (int k = 0; k < 64; ++k) {
        const float xc = xv[k % DEPTH];            // static slot index
        if (k + DEPTH < 64) {                      // compile-time guard
            const int c = rl_i(idx, k + DEPTH);    // immediate readlane
            xv[k % DEPTH] = x[((size_t)(unsigned)c << 6) + lane];
        }
        acc = fmaf(rl_f(v, k), xc, acc);           // immediate readlane
        if ((k & (SLOTS - 1)) == SLOTS - 1) {      // compile-time flush point
            const int qk = k >> (6 - LOG_RPW);     // compile-time row-of-group
            y[((size_t)(r0 + qk) << 6) + lane] = acc + ovf[qk];
            acc = 0.0f;
        }
    }
}

static inline int blocks_for_waves(int waves) {
    return (waves + 3) / 4;  // 4 waves (256 threads) per block
}

extern "C" void kernel_launch(void* const* d_in, const int* in_sizes, int n_in,
                              void* d_out, int out_size, void* d_ws, size_t ws_size,
                              hipStream_t stream) {
    const float* item_emb = (const float*)d_in[0];
    const float* S_vals   = (const float*)d_in[1];
    const int*   S_rows   = (const int*)  d_in[2];
    const int*   S_cols   = (const int*)  d_in[3];
    const float* urm_vals = (const float*)d_in[4];
    const int*   urm_rows = (const int*)  d_in[5];
    const int*   urm_cols = (const int*)  d_in[6];

    const int nnzS = in_sizes[1];
    const int nnzU = in_sizes[4];

    float* user_out = (float*)d_out;          // U*E floats (output 0)
    float* x_out    = (float*)d_out + UE;     // I*E floats (output 1)

    // Workspace: row_ptr for S (I+1 ints) and URM (U+1 ints), 256B-aligned.
    int* rpS = (int*)d_ws;
    size_t rpS_bytes = ((size_t)(I_CNT + 1) * sizeof(int) + 255) & ~(size_t)255;
    int* rpU = (int*)((char*)d_ws + rpS_bytes);

    const dim3 blk(256);

    // Build CSR row pointers (rows arrays are sorted).
    build_row_ptr<<<(nnzS + 255) / 256, blk, 0, stream>>>(S_rows, rpS, nnzS, I_CNT);
    build_row_ptr<<<(nnzU + 255) / 256, blk, 0, stream>>>(urm_rows, rpU, nnzU, U_CNT);

    // S hops: 2 rows/wave x 32 slots (row len ~Poisson(15); P(>32) ~ 1e-5).
    const int wS = I_CNT / 2;
    // hop 1: item_emb -> x_out (x1)
    spmm_slots<false, 1><<<blocks_for_waves(wS), blk, 0, stream>>>(
        S_vals, rpS, S_cols, item_emb, x_out, I_CNT, nnzS);
    // hop 2: x_out -> user region used as temp (x2; IE < UE, fits)
    spmm_slots<false, 1><<<blocks_for_waves(wS), blk, 0, stream>>>(
        S_vals, rpS, S_cols, x_out, user_out, I_CNT, nnzS);
    // hop 3: temp (x2) -> x_out (x3 = final x output)
    spmm_slots<false, 1><<<blocks_for_waves(wS), blk, 0, stream>>>(
        S_vals, rpS, S_cols, user_out, x_out, I_CNT, nnzS);

    // URM: 1 row/wave x 64 slots (row len ~Poisson(32); P(>64) ~ 1e-8, cold
    // overflow path still correct). Dropout uses original edge index s+j.
    spmm_slots<true, 0><<<blocks_for_waves(U_CNT), blk, 0, stream>>>(
        urm_vals, rpU, urm_cols, x_out, user_out, U_CNT, nnzU);
}